// Round 8
// baseline (512.494 us; speedup 1.0000x reference)
//
#include <hip/hip_runtime.h>
#include <hip/hip_bf16.h>
#include <math.h>

// ---------------------------------------------------------------------------
// torso_left_right_actor: x@W0+b0 -> GraphConv -> tanh -> GraphConv -> tanh
//   -> @W3+b3 -> tanh -> global_mean_pool -> NormalParamExtractor
// R8: k_conv persistent row-tile loop (weights staged ONCE per block,
//     1280 blocks = 5/CU at the 32KB-LDS limit). R6's k_fill binning and
//     shfl k_gather unchanged. bf16 features, f32 accumulation.
// ---------------------------------------------------------------------------

#define CAP 64
#define FILL_PARTS 8
#define FILL_BPP 1024   // blocks per partition
#define CONV_BLOCKS 1280
typedef __hip_bfloat16 bf16;

__device__ inline void storev(float* p, float v) { *p = v; }
__device__ inline void storev(bf16* p, float v) { *p = __float2bfloat16(v); }

// h = bf16(x @ W0 + b0)   (x: [N,11], W0: [11,64])
__global__ __launch_bounds__(256) void k_in(const float* __restrict__ x,
    const float* __restrict__ W0, const float* __restrict__ b0,
    bf16* __restrict__ h, int N) {
  __shared__ float w[11 * 64];
  __shared__ float xl[4][12];
  int tid = threadIdx.x;
  for (int i = tid; i < 11 * 64; i += 256) w[i] = W0[i];
  int row0 = blockIdx.x * 4;
  if (tid < 44) {
    int r = tid / 11, k = tid % 11;
    int g = row0 + r;
    xl[r][k] = (g < N) ? x[(size_t)g * 11 + k] : 0.f;
  }
  __syncthreads();
  int c = tid & 63, r = tid >> 6;
  int g = row0 + r;
  float acc = b0[c];
#pragma unroll
  for (int k = 0; k < 11; ++k) acc += xl[r][k] * w[k * 64 + c];
  if (g < N) h[(size_t)g * 64 + c] = __float2bfloat16(acc);
}

// CSR build, dst-range binned. Block b: partition p=b&7 (contiguous node
// range -> 3.2MB CSR slice, XCD-L2-local under round-robin block->XCD),
// edge-slice sb=b>>3. cnt must be pre-zeroed.
__global__ __launch_bounds__(256) void k_fill(const int* __restrict__ ei,
    int* __restrict__ cnt, int* __restrict__ csr, int E, int N) {
  int p  = blockIdx.x & 7;
  int sb = blockIdx.x >> 3;
  int nb = gridDim.x >> 3;
  int part = (N + 7) >> 3;
  int lo = p * part, hi = min(N, lo + part);
  const int* src = ei;
  const int* dst = ei + E;
  int E4 = E >> 2;
  const int4* d4 = (const int4*)dst;
  for (int i = sb * 256 + threadIdx.x; i < E4; i += nb * 256) {
    int4 dv = d4[i];
#pragma unroll
    for (int k = 0; k < 4; ++k) {
      int d = (&dv.x)[k];
      if (d >= lo && d < hi) {
        int s = src[i * 4 + k];
        int pos = atomicAdd(&cnt[d], 1);
        if (pos < CAP) csr[(size_t)d * CAP + pos] = s;
      }
    }
  }
  if (sb == 0 && threadIdx.x < (E & 3)) {   // tail edges
    int e = (E4 << 2) + threadIdx.x;
    int d = dst[e];
    if (d >= lo && d < hi) {
      int s = src[e];
      int pos = atomicAdd(&cnt[d], 1);
      if (pos < CAP) csr[(size_t)d * CAP + pos] = s;
    }
  }
}

// agg[n][c] = sum_{j in N(n)} h[j][c]. One wave per node, lane = feature.
// Lane c loads CSR slot c (coalesced), indices broadcast via shfl ->
// all h-row loads independent.
__global__ __launch_bounds__(256) void k_gather(const bf16* __restrict__ h,
    const int* __restrict__ csr, const int* __restrict__ cnt,
    float* __restrict__ agg, int N) {
  int wid = __builtin_amdgcn_readfirstlane(threadIdx.x >> 6);
  int node = blockIdx.x * 4 + wid;
  if (node >= N) return;
  int c = threadIdx.x & 63;
  int deg = min(cnt[node], CAP);              // wave-uniform (broadcast load)
  int myidx = csr[(size_t)node * CAP + c];    // coalesced 256B row read
  float a0 = 0.f, a1 = 0.f, a2 = 0.f, a3 = 0.f;
  int j = 0;
  for (; j + 4 <= deg; j += 4) {
    int s0 = __shfl(myidx, j + 0);
    int s1 = __shfl(myidx, j + 1);
    int s2 = __shfl(myidx, j + 2);
    int s3 = __shfl(myidx, j + 3);
    a0 += __bfloat162float(h[(size_t)s0 * 64 + c]);
    a1 += __bfloat162float(h[(size_t)s1 * 64 + c]);
    a2 += __bfloat162float(h[(size_t)s2 * 64 + c]);
    a3 += __bfloat162float(h[(size_t)s3 * 64 + c]);
  }
  for (; j < deg; ++j)
    a0 += __bfloat162float(h[(size_t)__shfl(myidx, j) * 64 + c]);
  agg[(size_t)node * 64 + c] = (a0 + a1) + (a2 + a3);
}

// out = tanh(A @ Wrel + brel + H @ Wroot)   (A: [N,64] f32; H: [N,64] bf16)
// Persistent blocks: weights staged into LDS ONCE, then grid-stride over
// 16-row tiles (4 rows/wave, wave-uniform row base -> broadcast loads).
// out may alias A or H (tile-local: all reads of a tile precede its stores).
template <typename OT>
__global__ __launch_bounds__(256) void k_conv(const float* A, const bf16* H,
    const float* __restrict__ Wrel, const float* __restrict__ brel,
    const float* __restrict__ Wroot, OT* out, int N) {
  __shared__ float wr[64 * 64], wo[64 * 64];
  int tid = threadIdx.x;
  for (int i = tid * 4; i < 64 * 64; i += 1024) {
    *(float4*)(wr + i) = *(const float4*)(Wrel + i);
    *(float4*)(wo + i) = *(const float4*)(Wroot + i);
  }
  __syncthreads();
  int c = tid & 63;
  int rg = __builtin_amdgcn_readfirstlane(tid >> 6);
  float b = brel[c];
  int nt = (N + 15) >> 4;
  for (int t = blockIdx.x; t < nt; t += gridDim.x) {
    int row0 = t * 16 + rg * 4;
    if (row0 >= N) continue;
    int r0 = min(row0 + 0, N - 1);
    int r1 = min(row0 + 1, N - 1);
    int r2 = min(row0 + 2, N - 1);
    int r3 = min(row0 + 3, N - 1);
    float acc0 = b, acc1 = b, acc2 = b, acc3 = b;
    for (int k4 = 0; k4 < 64; k4 += 4) {
      float4 a0 = *(const float4*)(A + (size_t)r0 * 64 + k4);
      float4 a1 = *(const float4*)(A + (size_t)r1 * 64 + k4);
      float4 a2 = *(const float4*)(A + (size_t)r2 * 64 + k4);
      float4 a3 = *(const float4*)(A + (size_t)r3 * 64 + k4);
      bf16 h0[4], h1[4], h2[4], h3[4];
      *(uint2*)h0 = *(const uint2*)(H + (size_t)r0 * 64 + k4);
      *(uint2*)h1 = *(const uint2*)(H + (size_t)r1 * 64 + k4);
      *(uint2*)h2 = *(const uint2*)(H + (size_t)r2 * 64 + k4);
      *(uint2*)h3 = *(const uint2*)(H + (size_t)r3 * 64 + k4);
#pragma unroll
      for (int kk = 0; kk < 4; ++kk) {
        float w1 = wr[(k4 + kk) * 64 + c];
        float w2 = wo[(k4 + kk) * 64 + c];
        acc0 += (&a0.x)[kk] * w1 + __bfloat162float(h0[kk]) * w2;
        acc1 += (&a1.x)[kk] * w1 + __bfloat162float(h1[kk]) * w2;
        acc2 += (&a2.x)[kk] * w1 + __bfloat162float(h2[kk]) * w2;
        acc3 += (&a3.x)[kk] * w1 + __bfloat162float(h3[kk]) * w2;
      }
    }
    if (row0 + 0 < N) storev(out + (size_t)(row0 + 0) * 64 + c, tanhf(acc0));
    if (row0 + 1 < N) storev(out + (size_t)(row0 + 1) * 64 + c, tanhf(acc1));
    if (row0 + 2 < N) storev(out + (size_t)(row0 + 2) * 64 + c, tanhf(acc2));
    if (row0 + 3 < N) storev(out + (size_t)(row0 + 3) * 64 + c, tanhf(acc3));
  }
}

// h3 = tanh(h2 @ W3 + b3)   (h2: [N,64] f32, W3: [64,16])
__global__ __launch_bounds__(256) void k_h3(const float* __restrict__ h2,
    const float* __restrict__ W3, const float* __restrict__ b3,
    float* __restrict__ h3, int N) {
  __shared__ float w[64 * 16];
  int tid = threadIdx.x;
  for (int i = tid; i < 64 * 16; i += 256) w[i] = W3[i];
  __syncthreads();
  int c = tid & 15, rg = tid >> 4;
  int row0 = blockIdx.x * 64;
#pragma unroll
  for (int i = 0; i < 4; ++i) {
    int row = row0 + rg + i * 16;
    int rowc = min(row, N - 1);
    float acc = b3[c];
    for (int k4 = 0; k4 < 64; k4 += 4) {
      float4 hv = *(const float4*)(h2 + (size_t)rowc * 64 + k4);
#pragma unroll
      for (int kk = 0; kk < 4; ++kk) acc += (&hv.x)[kk] * w[(k4 + kk) * 16 + c];
    }
    if (row < N) h3[(size_t)row * 16 + c] = tanhf(acc);
  }
}

// Per-graph mean pool + NormalParamExtractor. batch is sorted.
__global__ __launch_bounds__(256) void k_pool(const float* __restrict__ h3,
    const int* __restrict__ batch, float* __restrict__ out, int N, int B) {
  __shared__ int srange[2];
  __shared__ float red[256];
  int b = blockIdx.x;
  int tid = threadIdx.x;
  if (tid < 2) {
    int target = b + tid;
    int lo = 0, hi = N;
    while (lo < hi) {
      int mid = (lo + hi) >> 1;
      if (batch[mid] < target) lo = mid + 1; else hi = mid;
    }
    srange[tid] = lo;
  }
  __syncthreads();
  int s = srange[0], e = srange[1];
  int f = tid & 15, g = tid >> 4;
  float acc = 0.f;
  for (int n = s + g; n < e; n += 16) acc += h3[(size_t)n * 16 + f];
  red[tid] = acc;
  __syncthreads();
  for (int stride = 128; stride >= 16; stride >>= 1) {
    if (tid < stride) red[tid] += red[tid + stride];
    __syncthreads();
  }
  if (tid < 16) {
    float cnt = (float)(e - s);
    float pooled = red[tid] / fmaxf(cnt, 1.0f);
    if (tid < 8) {
      out[(size_t)b * 8 + tid] = pooled;
    } else {
      float xx = pooled + 0.54132485461292f;  // log(expm1(1.0))
      float sp = (xx > 20.f) ? xx : log1pf(expf(xx));
      out[(size_t)B * 8 + (size_t)b * 8 + (tid - 8)] = fmaxf(sp, 1e-4f);
    }
  }
}

extern "C" void kernel_launch(void* const* d_in, const int* in_sizes, int n_in,
                              void* d_out, int out_size, void* d_ws, size_t ws_size,
                              hipStream_t stream) {
  const float* x      = (const float*)d_in[0];
  const int*   ei     = (const int*)d_in[1];
  const int*   batch  = (const int*)d_in[2];
  const float* W0     = (const float*)d_in[3];
  const float* b0     = (const float*)d_in[4];
  const float* Wrel1  = (const float*)d_in[5];
  const float* brel1  = (const float*)d_in[6];
  const float* Wroot1 = (const float*)d_in[7];
  const float* Wrel2  = (const float*)d_in[8];
  const float* brel2  = (const float*)d_in[9];
  const float* Wroot2 = (const float*)d_in[10];
  const float* W3     = (const float*)d_in[11];
  const float* b3     = (const float*)d_in[12];
  float* out = (float*)d_out;

  int N = in_sizes[0] / 11;
  int E = in_sizes[1] / 2;
  int B = out_size / 16;

  bf16*  hb  = (bf16*)d_ws;                       // [N,64] bf16 (h0, then h1)
  float* agg = (float*)(hb + (size_t)N * 64);     // [N,64] f32 (agg, then h2)
  float* h3b = agg + (size_t)N * 64;              // [N,16] f32
  int*   cnt = (int*)(h3b + (size_t)N * 16);      // [N]
  int*   csr = cnt + N;                           // [N,CAP]

  // CSR build (reused by both conv layers)
  hipMemsetAsync(cnt, 0, (size_t)N * sizeof(int), stream);
  k_in<<<(N + 3) / 4, 256, 0, stream>>>(x, W0, b0, hb, N);
  k_fill<<<FILL_PARTS * FILL_BPP, 256, 0, stream>>>(ei, cnt, csr, E, N);

  // conv1 (out in-place over hb)
  k_gather<<<(N + 3) / 4, 256, 0, stream>>>(hb, csr, cnt, agg, N);
  k_conv<bf16><<<CONV_BLOCKS, 256, 0, stream>>>(agg, hb, Wrel1, brel1, Wroot1, hb, N);

  // conv2 (out f32, in-place over agg -> becomes h2)
  k_gather<<<(N + 3) / 4, 256, 0, stream>>>(hb, csr, cnt, agg, N);
  k_conv<float><<<CONV_BLOCKS, 256, 0, stream>>>(agg, hb, Wrel2, brel2, Wroot2, agg, N);

  // head
  k_h3<<<(N + 63) / 64, 256, 0, stream>>>(agg, W3, b3, h3b, N);
  k_pool<<<B, 256, 0, stream>>>(h3b, batch, out, N, B);
}

// Round 10
// 312.392 us; speedup vs baseline: 1.6405x; 1.6405x over previous
//
#include <hip/hip_runtime.h>
#include <hip/hip_bf16.h>
#include <math.h>

// ---------------------------------------------------------------------------
// torso_left_right_actor: x@W0+b0 -> GraphConv -> tanh -> GraphConv -> tanh
//   -> @W3+b3 -> tanh -> global_mean_pool -> NormalParamExtractor
// R10 = R9 resubmit (broker timeout, no measurement):
//     MFMA conv. Each block = 64-row supertile; each wave computes a 16x64
//     output tile via 16x16x32 bf16 MFMAs with weights in registers
//     (B-frags built once from LDS-staged W). All node tensors bf16.
//     Frag layouts: A row=lane&15,k=8*(lane>>4)+i; B col=lane&15 same k;
//     C/D col=lane&15,row=(lane>>4)*4+reg (m89-verified).
// ---------------------------------------------------------------------------

#define CAP 64
#define FILL_PARTS 8
#define FILL_BPP 1024
typedef __hip_bfloat16 bf16;
typedef __attribute__((ext_vector_type(8))) short bf16x8;
typedef __attribute__((ext_vector_type(4))) float f32x4;

// h = bf16(x @ W0 + b0)   (x: [N,11], W0: [11,64])
__global__ __launch_bounds__(256) void k_in(const float* __restrict__ x,
    const float* __restrict__ W0, const float* __restrict__ b0,
    bf16* __restrict__ h, int N) {
  __shared__ float w[11 * 64];
  __shared__ float xl[4][12];
  int tid = threadIdx.x;
  for (int i = tid; i < 11 * 64; i += 256) w[i] = W0[i];
  int row0 = blockIdx.x * 4;
  if (tid < 44) {
    int r = tid / 11, k = tid % 11;
    int g = row0 + r;
    xl[r][k] = (g < N) ? x[(size_t)g * 11 + k] : 0.f;
  }
  __syncthreads();
  int c = tid & 63, r = tid >> 6;
  int g = row0 + r;
  float acc = b0[c];
#pragma unroll
  for (int k = 0; k < 11; ++k) acc += xl[r][k] * w[k * 64 + c];
  if (g < N) h[(size_t)g * 64 + c] = __float2bfloat16(acc);
}

// CSR build, dst-range binned (8 partitions -> XCD-L2-local RMW).
// cnt must be pre-zeroed.
__global__ __launch_bounds__(256) void k_fill(const int* __restrict__ ei,
    int* __restrict__ cnt, int* __restrict__ csr, int E, int N) {
  int p  = blockIdx.x & 7;
  int sb = blockIdx.x >> 3;
  int nb = gridDim.x >> 3;
  int part = (N + 7) >> 3;
  int lo = p * part, hi = min(N, lo + part);
  const int* src = ei;
  const int* dst = ei + E;
  int E4 = E >> 2;
  const int4* d4 = (const int4*)dst;
  for (int i = sb * 256 + threadIdx.x; i < E4; i += nb * 256) {
    int4 dv = d4[i];
#pragma unroll
    for (int k = 0; k < 4; ++k) {
      int d = (&dv.x)[k];
      if (d >= lo && d < hi) {
        int s = src[i * 4 + k];
        int pos = atomicAdd(&cnt[d], 1);
        if (pos < CAP) csr[(size_t)d * CAP + pos] = s;
      }
    }
  }
  if (sb == 0 && threadIdx.x < (E & 3)) {   // tail edges
    int e = (E4 << 2) + threadIdx.x;
    int d = dst[e];
    if (d >= lo && d < hi) {
      int s = src[e];
      int pos = atomicAdd(&cnt[d], 1);
      if (pos < CAP) csr[(size_t)d * CAP + pos] = s;
    }
  }
}

// agg[n][c] = bf16( sum_{j in N(n)} h[j][c] ). One wave per node.
// Lane c loads CSR slot c coalesced; indices broadcast via shfl.
__global__ __launch_bounds__(256) void k_gather(const bf16* __restrict__ h,
    const int* __restrict__ csr, const int* __restrict__ cnt,
    bf16* __restrict__ agg, int N) {
  int wid = __builtin_amdgcn_readfirstlane(threadIdx.x >> 6);
  int node = blockIdx.x * 4 + wid;
  if (node >= N) return;
  int c = threadIdx.x & 63;
  int deg = min(cnt[node], CAP);              // wave-uniform
  int myidx = csr[(size_t)node * CAP + c];    // coalesced 256B row read
  float a0 = 0.f, a1 = 0.f, a2 = 0.f, a3 = 0.f;
  int j = 0;
  for (; j + 4 <= deg; j += 4) {
    int s0 = __shfl(myidx, j + 0);
    int s1 = __shfl(myidx, j + 1);
    int s2 = __shfl(myidx, j + 2);
    int s3 = __shfl(myidx, j + 3);
    a0 += __bfloat162float(h[(size_t)s0 * 64 + c]);
    a1 += __bfloat162float(h[(size_t)s1 * 64 + c]);
    a2 += __bfloat162float(h[(size_t)s2 * 64 + c]);
    a3 += __bfloat162float(h[(size_t)s3 * 64 + c]);
  }
  for (; j < deg; ++j)
    a0 += __bfloat162float(h[(size_t)__shfl(myidx, j) * 64 + c]);
  agg[(size_t)node * 64 + c] = __float2bfloat16((a0 + a1) + (a2 + a3));
}

// out = bf16(tanh(A @ Wrel + brel + H @ Wroot)), all [N,64] bf16.
// One 64-row supertile per block, 16 rows per wave, MFMA 16x16x32.
// out may alias A or H: each wave reads only its own 16 rows before storing.
__global__ __launch_bounds__(256) void k_convm(const bf16* A, const bf16* H,
    const float* __restrict__ Wrel, const float* __restrict__ brel,
    const float* __restrict__ Wroot, bf16* out, int N) {
  __shared__ float wlds[2][64 * 64];
  int tid = threadIdx.x;
  for (int i = tid * 4; i < 64 * 64; i += 1024) {
    *(float4*)(&wlds[0][i]) = *(const float4*)(Wrel + i);
    *(float4*)(&wlds[1][i]) = *(const float4*)(Wroot + i);
  }
  __syncthreads();
  int lane = tid & 63;
  int wv = __builtin_amdgcn_readfirstlane(tid >> 6);
  int lr = lane & 15;   // frag col/row index
  int lk = lane >> 4;   // k-group (x8) for A/B; D row-group (x4)

  // B-frags: lane holds W[k = lk*8+i+ks*32][col = lr+cb*16], i=0..7
  bf16x8 wr[4][2], wo[4][2];
#pragma unroll
  for (int cb = 0; cb < 4; ++cb) {
#pragma unroll
    for (int ks = 0; ks < 2; ++ks) {
      bf16* pr = (bf16*)&wr[cb][ks];
      bf16* po = (bf16*)&wo[cb][ks];
#pragma unroll
      for (int i = 0; i < 8; ++i) {
        int k = lk * 8 + i + ks * 32;
        int col = lr + cb * 16;
        pr[i] = __float2bfloat16(wlds[0][k * 64 + col]);
        po[i] = __float2bfloat16(wlds[1][k * 64 + col]);
      }
    }
  }
  float bias[4];
#pragma unroll
  for (int cb = 0; cb < 4; ++cb) bias[cb] = brel[lr + cb * 16];

  int rb = blockIdx.x * 64 + wv * 16;
  if (rb >= N) return;
  // A-frags: lane holds A[row = rb+lr][k = lk*8+i (+32)]
  int arow = min(rb + lr, N - 1);
  const bf16x8* Ap = (const bf16x8*)(A + (size_t)arow * 64 + lk * 8);
  const bf16x8* Hp = (const bf16x8*)(H + (size_t)arow * 64 + lk * 8);
  bf16x8 a0 = Ap[0], a1 = Ap[4];   // +4 bf16x8 = +32 elements (ks=1)
  bf16x8 h0 = Hp[0], h1 = Hp[4];

  f32x4 acc[4];
#pragma unroll
  for (int cb = 0; cb < 4; ++cb) {
    f32x4 c0 = {bias[cb], bias[cb], bias[cb], bias[cb]};
    c0 = __builtin_amdgcn_mfma_f32_16x16x32_bf16(a0, wr[cb][0], c0, 0, 0, 0);
    c0 = __builtin_amdgcn_mfma_f32_16x16x32_bf16(a1, wr[cb][1], c0, 0, 0, 0);
    c0 = __builtin_amdgcn_mfma_f32_16x16x32_bf16(h0, wo[cb][0], c0, 0, 0, 0);
    c0 = __builtin_amdgcn_mfma_f32_16x16x32_bf16(h1, wo[cb][1], c0, 0, 0, 0);
    acc[cb] = c0;
  }
  // D: col = lr+cb*16, row = rb + lk*4 + r
#pragma unroll
  for (int cb = 0; cb < 4; ++cb) {
#pragma unroll
    for (int r = 0; r < 4; ++r) {
      int row = rb + lk * 4 + r;
      if (row < N)
        out[(size_t)row * 64 + lr + cb * 16] = __float2bfloat16(tanhf(acc[cb][r]));
    }
  }
}

// h3 = tanh(h2 @ W3 + b3)   (h2: [N,64] bf16, W3: [64,16])
__global__ __launch_bounds__(256) void k_h3(const bf16* __restrict__ h2,
    const float* __restrict__ W3, const float* __restrict__ b3,
    float* __restrict__ h3, int N) {
  __shared__ float w[64 * 16];
  int tid = threadIdx.x;
  for (int i = tid; i < 64 * 16; i += 256) w[i] = W3[i];
  __syncthreads();
  int c = tid & 15, rg = tid >> 4;
  int row0 = blockIdx.x * 64;
#pragma unroll
  for (int i = 0; i < 4; ++i) {
    int row = row0 + rg + i * 16;
    int rowc = min(row, N - 1);
    float acc = b3[c];
    for (int k8 = 0; k8 < 64; k8 += 8) {
      bf16 hv[8];
      *(uint4*)hv = *(const uint4*)(h2 + (size_t)rowc * 64 + k8);
#pragma unroll
      for (int kk = 0; kk < 8; ++kk)
        acc += __bfloat162float(hv[kk]) * w[(k8 + kk) * 16 + c];
    }
    if (row < N) h3[(size_t)row * 16 + c] = tanhf(acc);
  }
}

// Per-graph mean pool + NormalParamExtractor. batch is sorted.
__global__ __launch_bounds__(256) void k_pool(const float* __restrict__ h3,
    const int* __restrict__ batch, float* __restrict__ out, int N, int B) {
  __shared__ int srange[2];
  __shared__ float red[256];
  int b = blockIdx.x;
  int tid = threadIdx.x;
  if (tid < 2) {
    int target = b + tid;
    int lo = 0, hi = N;
    while (lo < hi) {
      int mid = (lo + hi) >> 1;
      if (batch[mid] < target) lo = mid + 1; else hi = mid;
    }
    srange[tid] = lo;
  }
  __syncthreads();
  int s = srange[0], e = srange[1];
  int f = tid & 15, g = tid >> 4;
  float acc = 0.f;
  for (int n = s + g; n < e; n += 16) acc += h3[(size_t)n * 16 + f];
  red[tid] = acc;
  __syncthreads();
  for (int stride = 128; stride >= 16; stride >>= 1) {
    if (tid < stride) red[tid] += red[tid + stride];
    __syncthreads();
  }
  if (tid < 16) {
    float cnt = (float)(e - s);
    float pooled = red[tid] / fmaxf(cnt, 1.0f);
    if (tid < 8) {
      out[(size_t)b * 8 + tid] = pooled;
    } else {
      float xx = pooled + 0.54132485461292f;  // log(expm1(1.0))
      float sp = (xx > 20.f) ? xx : log1pf(expf(xx));
      out[(size_t)B * 8 + (size_t)b * 8 + (tid - 8)] = fmaxf(sp, 1e-4f);
    }
  }
}

extern "C" void kernel_launch(void* const* d_in, const int* in_sizes, int n_in,
                              void* d_out, int out_size, void* d_ws, size_t ws_size,
                              hipStream_t stream) {
  const float* x      = (const float*)d_in[0];
  const int*   ei     = (const int*)d_in[1];
  const int*   batch  = (const int*)d_in[2];
  const float* W0     = (const float*)d_in[3];
  const float* b0     = (const float*)d_in[4];
  const float* Wrel1  = (const float*)d_in[5];
  const float* brel1  = (const float*)d_in[6];
  const float* Wroot1 = (const float*)d_in[7];
  const float* Wrel2  = (const float*)d_in[8];
  const float* brel2  = (const float*)d_in[9];
  const float* Wroot2 = (const float*)d_in[10];
  const float* W3     = (const float*)d_in[11];
  const float* b3     = (const float*)d_in[12];
  float* out = (float*)d_out;

  int N = in_sizes[0] / 11;
  int E = in_sizes[1] / 2;
  int B = out_size / 16;

  bf16*  hb   = (bf16*)d_ws;                      // [N,64] bf16 (h0 -> h1)
  bf16*  aggb = hb + (size_t)N * 64;              // [N,64] bf16 (agg -> h2)
  float* h3b  = (float*)(aggb + (size_t)N * 64);  // [N,16] f32
  int*   cnt  = (int*)(h3b + (size_t)N * 16);     // [N]
  int*   csr  = cnt + N;                          // [N,CAP]

  int nst = (N + 63) / 64;  // conv supertiles

  // CSR build (reused by both conv layers)
  hipMemsetAsync(cnt, 0, (size_t)N * sizeof(int), stream);
  k_in<<<(N + 3) / 4, 256, 0, stream>>>(x, W0, b0, hb, N);
  k_fill<<<FILL_PARTS * FILL_BPP, 256, 0, stream>>>(ei, cnt, csr, E, N);

  // conv1 (out in-place over hb)
  k_gather<<<(N + 3) / 4, 256, 0, stream>>>(hb, csr, cnt, aggb, N);
  k_convm<<<nst, 256, 0, stream>>>(aggb, hb, Wrel1, brel1, Wroot1, hb, N);

  // conv2 (out in-place over aggb -> becomes h2)
  k_gather<<<(N + 3) / 4, 256, 0, stream>>>(hb, csr, cnt, aggb, N);
  k_convm<<<nst, 256, 0, stream>>>(aggb, hb, Wrel2, brel2, Wroot2, aggb, N);

  // head
  k_h3<<<(N + 63) / 64, 256, 0, stream>>>(aggb, W3, b3, h3b, N);
  k_pool<<<B, 256, 0, stream>>>(h3b, batch, out, N, B);
}